// Round 7
// baseline (352.937 us; speedup 1.0000x reference)
//
#include <hip/hip_runtime.h>

typedef _Float16 f16;
typedef __attribute__((ext_vector_type(4))) _Float16 f16x4;
typedef __attribute__((ext_vector_type(8))) _Float16 f16x8;
typedef __attribute__((ext_vector_type(4))) float f32x4;
typedef __attribute__((ext_vector_type(16))) float f32x16;
typedef unsigned int u32;

#define BB 32
#define LL 1024
#define DD 256

// async global->LDS, 16B per lane, dst = ldsbase + lane*16 (wave-uniform base)
__device__ __forceinline__ void async_copy16(const f16* g, f16* l) {
  __builtin_amdgcn_global_load_lds(
      (const __attribute__((address_space(1))) u32*)(const void*)g,
      (__attribute__((address_space(3))) u32*)(void*)l, 16, 0, 0);
}

// pack two f32 -> f16x2 in a u32 (v_cvt_pkrtz_f16_f32)
__device__ __forceinline__ u32 pack_pkrtz(float a, float b) {
  auto pk = __builtin_amdgcn_cvt_pkrtz(a, b);  // __fp16 ext_vector(2)
  u32 w;
  __builtin_memcpy(&w, &pk, 4);
  return w;
}

// ---------------------------------------------------------------------------
// Transpose + fp32->fp16 (used only for the tiny W^T).
// ---------------------------------------------------------------------------
__global__ __launch_bounds__(256) void transpose_to_f16(
    const float* __restrict__ X0, f16* __restrict__ Y0, int L, int D) {
  __shared__ float T[64][68];
  const int tid = threadIdx.x;
  const float* X = X0;
  f16* Y = Y0;
  const int l0 = blockIdx.x * 64, d0 = blockIdx.y * 64;
#pragma unroll
  for (int pass = 0; pass < 4; ++pass) {
    int r = (tid >> 4) + pass * 16;
    int c = (tid & 15) * 4;
    float4 v = *(const float4*)&X[(size_t)(l0 + r) * D + d0 + c];
    *(float4*)&T[r][c] = v;
  }
  __syncthreads();
#pragma unroll
  for (int pass = 0; pass < 2; ++pass) {
    int dr = (tid >> 3) + pass * 32;
    int lc = (tid & 7) * 8;
    f16x8 o;
#pragma unroll
    for (int j = 0; j < 8; ++j) o[j] = (f16)T[lc + j][dr];
    *(f16x8*)&Y[(size_t)(d0 + dr) * L + l0 + lc] = o;
  }
}

// ---------------------------------------------------------------------------
// Projection v2: F = tanh(A @ W) f16  +  fused X^T f16 emit.
// Block = 64m x 256n, K=256 fully unrolled. A-frags direct from global (NT,
// read exactly once); W-frags direct from L2 (131 KB hot). As LDS only for
// the V^T emit. grid (512, 2) — y selects premises/hypotheses. 3 blocks/CU.
// ---------------------------------------------------------------------------
__global__ __launch_bounds__(256, 3) void proj_mfma(
    const float* __restrict__ Pin, const float* __restrict__ Hin,
    const f16* __restrict__ Wt, f16* __restrict__ Fp, f16* __restrict__ Fh,
    f16* __restrict__ Vtp, f16* __restrict__ Vth) {
  __shared__ f16 As[64][280];  // [m(l)][k(d)] f16 copy of A tile (for V^T emit)
  const int tid = threadIdx.x;
  const int wv = tid >> 6, lane = tid & 63, quad = lane >> 4, l16 = lane & 15;
  const float* A = blockIdx.y ? Hin : Pin;
  f16* F = blockIdx.y ? Fh : Fp;
  f16* VtO = blockIdx.y ? Vth : Vtp;
  const int m0 = blockIdx.x * 64;
  const int arow = m0 + wv * 16 + l16;  // A-frag: m = l16 (per wave 16 rows)

  f32x4 acc[16] = {};
  for (int s = 0; s < 8; ++s) {  // k-steps of 32
    const float* ap = A + (size_t)arow * 256 + s * 32 + quad * 8;
    f32x4 a0 = __builtin_nontemporal_load((const f32x4*)ap);
    f32x4 a1 = __builtin_nontemporal_load((const f32x4*)(ap + 4));
    u32 w[4];
    w[0] = pack_pkrtz(a0[0], a0[1]);
    w[1] = pack_pkrtz(a0[2], a0[3]);
    w[2] = pack_pkrtz(a1[0], a1[1]);
    w[3] = pack_pkrtz(a1[2], a1[3]);
    f16x8 af;
    __builtin_memcpy(&af, w, 16);
    *(f16x8*)&As[wv * 16 + l16][s * 32 + quad * 8] = af;
#pragma unroll
    for (int t = 0; t < 16; ++t) {
      f16x8 wf = *(const f16x8*)&Wt[(size_t)(t * 16 + l16) * 256 + s * 32 + quad * 8];
      acc[t] = __builtin_amdgcn_mfma_f32_16x16x32_f16(af, wf, acc[t], 0, 0, 0);
    }
  }

  // tanh epilogue + f16 store.  C layout: row = quad*4+r, col = l16.
#pragma unroll
  for (int t = 0; t < 16; ++t)
#pragma unroll
    for (int r = 0; r < 4; ++r) {
      float x = acc[t][r];
      float e = __expf(2.f * x);
      float th = 1.f - 2.f / (e + 1.f);
      F[(size_t)(m0 + wv * 16 + quad * 4 + r) * 256 + t * 16 + l16] = (f16)th;
    }

  // V^T emit: thread tid owns d-column = tid, 64 l's in 8 chunks
  __syncthreads();
  const int bI = m0 >> 10, l_base = m0 & 1023;
  f16* vcol = VtO + (size_t)bI * DD * LL + (size_t)tid * LL + l_base;
#pragma unroll
  for (int lo = 0; lo < 8; ++lo) {
    f16x8 ov;
#pragma unroll
    for (int j = 0; j < 8; ++j) ov[j] = As[lo * 8 + j][tid];
    *(f16x8*)&vcol[lo * 8] = ov;
  }
}

// ---------------------------------------------------------------------------
// Flash alignment v2: 32x32x16 MFMA, transposed formulation, TK=64.
//   S^T = K Q^T ; O^T = V^T P^T.  Wave owns 32 p-columns; in-lane softmax.
// LDS 64 KB fragment-order via global_load_lds(16B). 2 blocks/CU.
// 1D grid 512, swizzled so the 8 p-tiles of a (b,dir) pair share an XCD.
// ---------------------------------------------------------------------------
__global__ __launch_bounds__(256, 2) void flash_mfma(
    const f16* __restrict__ Fpm, const f16* __restrict__ Fhm,
    const f16* __restrict__ Vth, const f16* __restrict__ Vtp,
    float* __restrict__ Out) {
  __shared__ f16 Kf[32][512];  // frag f=qt*16+s: lane -> K[q0+qt*32+l32][s*16+half*8..]
  __shared__ f16 Vf[32][512];  // frag v=t*4+kk: lane -> V^T[t*32+l32][q0+kk*16+half*8..]

  const int tid = threadIdx.x;
  const int wv = tid >> 6, lane = tid & 63;
  const int l32 = lane & 31, half = lane >> 5;

  // swizzle: id%8 constant across the 8 p-tiles of one (b,dir) pair
  const int id = blockIdx.x;
  const int lo_ = id & 7, mid = (id >> 3) & 7, pt = id >> 6;
  const int pair = mid * 8 + lo_;  // 0..63
  const int dir = pair >> 5, b = pair & 31;

  const f16* Fq = dir ? Fhm : Fpm;
  const f16* Fk = dir ? Fpm : Fhm;
  const f16* Vt = dir ? Vtp : Vth;
  float* O = Out + (size_t)dir * BB * LL * DD;

  const int p = pt * 128 + wv * 32 + l32;  // this lane's p-column

  const f16* Fq_b = Fq + (size_t)b * LL * DD;
  const f16* Fk_b = Fk + (size_t)b * LL * DD;
  const f16* Vt_b = Vt + (size_t)b * DD * LL;

  // Q fragments (B-operand): n=p, k = s*16 + half*8 + j
  f16x8 qf[16];
  {
    const f16* qrow = Fq_b + (size_t)p * DD + half * 8;
#pragma unroll
    for (int s = 0; s < 16; ++s) qf[s] = *(const f16x8*)&qrow[s * 16];
  }

  float m_run = -1e30f, l_part = 0.f;
  f32x16 o[8];
#pragma unroll
  for (int t = 0; t < 8; ++t) o[t] = (f32x16)(0.f);

  for (int q0 = 0; q0 < LL; q0 += 64) {
    __syncthreads();  // previous tile's LDS reads complete
    // wave wv stages K frags wv*8..+7 and V frags wv*8..+7
#pragma unroll
    for (int i = 0; i < 8; ++i) {
      int f = wv * 8 + i;
      int qt = f >> 4, s = f & 15;
      async_copy16(Fk_b + (size_t)(q0 + qt * 32 + l32) * DD + s * 16 + half * 8,
                   &Kf[f][0]);
    }
#pragma unroll
    for (int i = 0; i < 8; ++i) {
      int v = wv * 8 + i;
      int t = v >> 2, kk = v & 3;
      async_copy16(Vt_b + (size_t)(t * 32 + l32) * LL + q0 + kk * 16 + half * 8,
                   &Vf[v][0]);
    }
    __syncthreads();  // DMA landed (barrier drains vmcnt)

    // S^T for both q-subtiles
    f32x16 S0 = (f32x16)(0.f), S1 = (f32x16)(0.f);
#pragma unroll
    for (int s = 0; s < 16; ++s) {
      f16x8 k0 = *(const f16x8*)&Kf[s][lane * 8];
      S0 = __builtin_amdgcn_mfma_f32_32x32x16_f16(k0, qf[s], S0, 0, 0, 0);
      f16x8 k1 = *(const f16x8*)&Kf[16 + s][lane * 8];
      S1 = __builtin_amdgcn_mfma_f32_32x32x16_f16(k1, qf[s], S1, 0, 0, 0);
    }

    // joint online softmax over 64 q (32 values in-lane + cross-half merge)
    float mt = S0[0];
#pragma unroll
    for (int r = 1; r < 16; ++r) mt = fmaxf(mt, S0[r]);
#pragma unroll
    for (int r = 0; r < 16; ++r) mt = fmaxf(mt, S1[r]);
    mt = fmaxf(mt, __shfl_xor(mt, 32, 64));
    const float mn = fmaxf(m_run, mt);
    float ts = 0.f;
#pragma unroll
    for (int r = 0; r < 16; ++r) {
      S0[r] = __expf(S0[r] - mn);
      ts += S0[r];
    }
#pragma unroll
    for (int r = 0; r < 16; ++r) {
      S1[r] = __expf(S1[r] - mn);
      ts += S1[r];
    }
    const float alpha = __expf(m_run - mn);
    l_part = l_part * alpha + ts;  // per-lane partial; halves merged at end
    m_run = mn;

    // rescale O^T once
#pragma unroll
    for (int t = 0; t < 8; ++t) o[t] *= alpha;

    // subtile 0: build P^T frags (ksteps 0,1) and accumulate
    {
      u32 pw[8];
#pragma unroll
      for (int i = 0; i < 8; ++i) pw[i] = pack_pkrtz(S0[2 * i], S0[2 * i + 1]);
      u32 rc[4];
      rc[0] = (u32)__shfl_xor((int)(half ? pw[0] : pw[2]), 32, 64);
      rc[1] = (u32)__shfl_xor((int)(half ? pw[1] : pw[3]), 32, 64);
      rc[2] = (u32)__shfl_xor((int)(half ? pw[4] : pw[6]), 32, 64);
      rc[3] = (u32)__shfl_xor((int)(half ? pw[5] : pw[7]), 32, 64);
      f16x8 pf[2];
#pragma unroll
      for (int h = 0; h < 2; ++h) {
        u32 tmp[4];
        tmp[0] = half ? rc[2 * h] : pw[4 * h];
        tmp[1] = half ? rc[2 * h + 1] : pw[4 * h + 1];
        tmp[2] = half ? pw[4 * h + 2] : rc[2 * h];
        tmp[3] = half ? pw[4 * h + 3] : rc[2 * h + 1];
        __builtin_memcpy(&pf[h], tmp, 16);
      }
#pragma unroll
      for (int t = 0; t < 8; ++t) {
        f16x8 v0 = *(const f16x8*)&Vf[t * 4 + 0][lane * 8];
        o[t] = __builtin_amdgcn_mfma_f32_32x32x16_f16(v0, pf[0], o[t], 0, 0, 0);
        f16x8 v1 = *(const f16x8*)&Vf[t * 4 + 1][lane * 8];
        o[t] = __builtin_amdgcn_mfma_f32_32x32x16_f16(v1, pf[1], o[t], 0, 0, 0);
      }
    }
    // subtile 1: ksteps 2,3
    {
      u32 pw[8];
#pragma unroll
      for (int i = 0; i < 8; ++i) pw[i] = pack_pkrtz(S1[2 * i], S1[2 * i + 1]);
      u32 rc[4];
      rc[0] = (u32)__shfl_xor((int)(half ? pw[0] : pw[2]), 32, 64);
      rc[1] = (u32)__shfl_xor((int)(half ? pw[1] : pw[3]), 32, 64);
      rc[2] = (u32)__shfl_xor((int)(half ? pw[4] : pw[6]), 32, 64);
      rc[3] = (u32)__shfl_xor((int)(half ? pw[5] : pw[7]), 32, 64);
      f16x8 pf[2];
#pragma unroll
      for (int h = 0; h < 2; ++h) {
        u32 tmp[4];
        tmp[0] = half ? rc[2 * h] : pw[4 * h];
        tmp[1] = half ? rc[2 * h + 1] : pw[4 * h + 1];
        tmp[2] = half ? pw[4 * h + 2] : rc[2 * h];
        tmp[3] = half ? pw[4 * h + 3] : rc[2 * h + 1];
        __builtin_memcpy(&pf[h], tmp, 16);
      }
#pragma unroll
      for (int t = 0; t < 8; ++t) {
        f16x8 v2 = *(const f16x8*)&Vf[t * 4 + 2][lane * 8];
        o[t] = __builtin_amdgcn_mfma_f32_32x32x16_f16(v2, pf[0], o[t], 0, 0, 0);
        f16x8 v3 = *(const f16x8*)&Vf[t * 4 + 3][lane * 8];
        o[t] = __builtin_amdgcn_mfma_f32_32x32x16_f16(v3, pf[1], o[t], 0, 0, 0);
      }
    }
  }

  const float l_run = l_part + __shfl_xor(l_part, 32, 64);
  const float inv = 1.f / l_run;
  // C layout: row(d within t*32) = (r&3) + 8*(r>>2) + 4*half; col = p
  float* orow = O + ((size_t)b * LL + p) * DD;
#pragma unroll
  for (int t = 0; t < 8; ++t) {
#pragma unroll
    for (int g = 0; g < 4; ++g) {
      f32x4 v;
      v[0] = o[t][4 * g + 0] * inv;
      v[1] = o[t][4 * g + 1] * inv;
      v[2] = o[t][4 * g + 2] * inv;
      v[3] = o[t][4 * g + 3] * inv;
      __builtin_nontemporal_store(v, (f32x4*)&orow[t * 32 + 8 * g + 4 * half]);
    }
  }
}

// ---------------------------------------------------------------------------
extern "C" void kernel_launch(void* const* d_in, const int* in_sizes, int n_in,
                              void* d_out, int out_size, void* d_ws,
                              size_t ws_size, hipStream_t stream) {
  const float* premises = (const float*)d_in[0];    // [32,1024,256] fp32
  const float* hypotheses = (const float*)d_in[1];  // [32,1024,256] fp32
  const float* W = (const float*)d_in[2];           // [256,256] fp32
  float* out = (float*)d_out;

  const size_t MF = (size_t)BB * LL * DD;
  f16* Fp = (f16*)d_ws;   // 16 MiB each; ws = 64 MiB exactly
  f16* Fh = Fp + MF;
  f16* Vth = Fh + MF;     // hypotheses^T [B][D][L] f16
  f16* Vtp = Vth + MF;    // premises^T   [B][D][L] f16
  // Wt (131 KB) stashed in d_out tail: used only by proj, overwritten by flash
  f16* Wt = (f16*)((char*)d_out + (size_t)out_size * 4 - 256 * 256 * 2);

  // W^T -> f16
  transpose_to_f16<<<dim3(4, 4), 256, 0, stream>>>(W, Wt, 256, 256);
  // F = tanh(X @ W) f16, + fused X^T f16 emit
  proj_mfma<<<dim3(512, 2), 256, 0, stream>>>(premises, hypotheses, Wt, Fp, Fh,
                                              Vtp, Vth);
  // betas + alphas in one swizzled 1D launch: 512 blocks = 2 blocks/CU
  flash_mfma<<<512, 256, 0, stream>>>(Fp, Fh, Vth, Vtp, out);
}

// Round 8
// 308.238 us; speedup vs baseline: 1.1450x; 1.1450x over previous
//
#include <hip/hip_runtime.h>

typedef _Float16 f16;
typedef __attribute__((ext_vector_type(4))) _Float16 f16x4;
typedef __attribute__((ext_vector_type(8))) _Float16 f16x8;
typedef __attribute__((ext_vector_type(4))) float f32x4;
typedef __attribute__((ext_vector_type(16))) float f32x16;
typedef unsigned int u32;

#define BB 32
#define LL 1024
#define DD 256

// async global->LDS, 16B per lane, dst = ldsbase + lane*16 (wave-uniform base)
__device__ __forceinline__ void async_copy16(const f16* g, f16* l) {
  __builtin_amdgcn_global_load_lds(
      (const __attribute__((address_space(1))) u32*)(const void*)g,
      (__attribute__((address_space(3))) u32*)(void*)l, 16, 0, 0);
}

// pack two f32 -> f16x2 in a u32 (v_cvt_pkrtz_f16_f32)
__device__ __forceinline__ u32 pack_pkrtz(float a, float b) {
  auto pk = __builtin_amdgcn_cvt_pkrtz(a, b);  // __fp16 ext_vector(2)
  u32 w;
  __builtin_memcpy(&w, &pk, 4);
  return w;
}

// ---------------------------------------------------------------------------
// Transpose + fp32->fp16 (used only for the tiny W^T).
// ---------------------------------------------------------------------------
__global__ __launch_bounds__(256) void transpose_to_f16(
    const float* __restrict__ X0, f16* __restrict__ Y0, int L, int D) {
  __shared__ float T[64][68];
  const int tid = threadIdx.x;
  const int l0 = blockIdx.x * 64, d0 = blockIdx.y * 64;
#pragma unroll
  for (int pass = 0; pass < 4; ++pass) {
    int r = (tid >> 4) + pass * 16;
    int c = (tid & 15) * 4;
    float4 v = *(const float4*)&X0[(size_t)(l0 + r) * D + d0 + c];
    *(float4*)&T[r][c] = v;
  }
  __syncthreads();
#pragma unroll
  for (int pass = 0; pass < 2; ++pass) {
    int dr = (tid >> 3) + pass * 32;
    int lc = (tid & 7) * 8;
    f16x8 o;
#pragma unroll
    for (int j = 0; j < 8; ++j) o[j] = (f16)T[lc + j][dr];
    *(f16x8*)&Y0[(size_t)(d0 + dr) * L + l0 + lc] = o;
  }
}

// ---------------------------------------------------------------------------
// Projection v3: F = tanh(A @ W) f16 + fused X^T f16 emit.
// Block = 64m x 256n. Per k-chunk (64): W frags staged in FRAGMENT ORDER via
// global_load_lds (conflict-free ds_read_b128, no L1 thrash); A loaded as
// plain coalesced register loads (2 KB/instr) overlapping the W DMA.
// As LDS (stride 72) only for the V^T emit. 41 KB LDS -> 3 blocks/CU.
// grid (512, 2) — y selects premises/hypotheses.
// ---------------------------------------------------------------------------
__global__ __launch_bounds__(256, 3) void proj_mfma(
    const float* __restrict__ Pin, const float* __restrict__ Hin,
    const f16* __restrict__ Wt, f16* __restrict__ Fp, f16* __restrict__ Fh,
    f16* __restrict__ Vtp, f16* __restrict__ Vth) {
  __shared__ f16 Wf[32][512];  // frag f=t*2+s: lane -> Wt[t*16+l16][kc*64+s*32+quad*8]
  __shared__ f16 As[64][72];   // [m][k64] f16 A chunk (V^T emit only)
  const int tid = threadIdx.x;
  const int wv = tid >> 6, lane = tid & 63, quad = lane >> 4, l16 = lane & 15;
  const float* A = blockIdx.y ? Hin : Pin;
  f16* F = blockIdx.y ? Fh : Fp;
  f16* VtO = blockIdx.y ? Vth : Vtp;
  const int m0 = blockIdx.x * 64;
  const int arow = m0 + wv * 16 + l16;
  const int bI = m0 >> 10, l_base = m0 & 1023;

  f32x4 acc[16] = {};
  for (int kc = 0; kc < 4; ++kc) {
    __syncthreads();  // Wf/As reusable (prev reads done)
    // stage 32 W frags for this k-chunk (8 per wave), fragment order
#pragma unroll
    for (int i = 0; i < 8; ++i) {
      int f = wv * 8 + i;  // f = t*2 + s
      int t = f >> 1, s = f & 1;
      async_copy16(
          Wt + (size_t)(t * 16 + l16) * 256 + kc * 64 + s * 32 + quad * 8,
          &Wf[f][0]);
    }
    // A: plain coalesced loads -> f16 frags in regs (overlaps W DMA)
    f16x8 af[2];
#pragma unroll
    for (int s = 0; s < 2; ++s) {
      const float* ap = A + (size_t)arow * 256 + kc * 64 + s * 32 + quad * 8;
      f32x4 a0 = *(const f32x4*)ap;
      f32x4 a1 = *(const f32x4*)(ap + 4);
      u32 w[4];
      w[0] = pack_pkrtz(a0[0], a0[1]);
      w[1] = pack_pkrtz(a0[2], a0[3]);
      w[2] = pack_pkrtz(a1[0], a1[1]);
      w[3] = pack_pkrtz(a1[2], a1[3]);
      __builtin_memcpy(&af[s], w, 16);
      *(f16x8*)&As[wv * 16 + l16][s * 32 + quad * 8] = af[s];
    }
    __syncthreads();  // Wf landed, As visible
#pragma unroll
    for (int s = 0; s < 2; ++s)
#pragma unroll
      for (int t = 0; t < 16; ++t) {
        f16x8 wf = *(const f16x8*)&Wf[t * 2 + s][lane * 8];  // conflict-free
        acc[t] = __builtin_amdgcn_mfma_f32_16x16x32_f16(af[s], wf, acc[t], 0, 0, 0);
      }
    // V^T emit for d in [kc*64, kc*64+64): thread -> d=lane, 16 l's (lg=wv)
    {
      const int dcol = tid & 63, lg = tid >> 6;
      f16* vcol = VtO + (size_t)bI * DD * LL + (size_t)(kc * 64 + dcol) * LL +
                  l_base + lg * 16;
      f16x8 ov0, ov1;
#pragma unroll
      for (int j = 0; j < 8; ++j) ov0[j] = As[lg * 16 + j][dcol];
#pragma unroll
      for (int j = 0; j < 8; ++j) ov1[j] = As[lg * 16 + 8 + j][dcol];
      *(f16x8*)&vcol[0] = ov0;
      *(f16x8*)&vcol[8] = ov1;
    }
  }

  // tanh epilogue + f16 store.  C layout: row = quad*4+r, col = l16.
#pragma unroll
  for (int t = 0; t < 16; ++t)
#pragma unroll
    for (int r = 0; r < 4; ++r) {
      float x = acc[t][r];
      float e = __expf(2.f * x);
      float th = 1.f - 2.f / (e + 1.f);
      F[(size_t)(m0 + wv * 16 + quad * 4 + r) * 256 + t * 16 + l16] = (f16)th;
    }
}

// ---------------------------------------------------------------------------
// Flash alignment v3: 32x32x16 MFMA, transposed formulation, TK=32,
// DOUBLE-BUFFERED: stage tile i+1 (global_load_lds) -> compute tile i ->
// one barrier.  The vmcnt drain at the barrier happens after a full compute
// phase, so DMA latency is hidden.  LDS 64 KB -> 2 blocks/CU.
// 1D grid 512, swizzled so the 8 p-tiles of a (b,dir) pair share an XCD.
// ---------------------------------------------------------------------------
__global__ __launch_bounds__(256, 2) void flash_mfma(
    const f16* __restrict__ Fpm, const f16* __restrict__ Fhm,
    const f16* __restrict__ Vth, const f16* __restrict__ Vtp,
    float* __restrict__ Out) {
  __shared__ f16 Kf[2][16][512];  // frag s: lane -> K[q0+l32][s*16+half*8..]
  __shared__ f16 Vf[2][16][512];  // frag v=t*2+h: lane -> V^T[t*32+l32][q0+h*16+half*8..]

  const int tid = threadIdx.x;
  const int wv = tid >> 6, lane = tid & 63;
  const int l32 = lane & 31, half = lane >> 5;

  // swizzle: id%8 constant across the 8 p-tiles of one (b,dir) pair
  const int id = blockIdx.x;
  const int lo_ = id & 7, mid = (id >> 3) & 7, pt = id >> 6;
  const int pair = mid * 8 + lo_;  // 0..63
  const int dir = pair >> 5, b = pair & 31;

  const f16* Fq = dir ? Fhm : Fpm;
  const f16* Fk = dir ? Fpm : Fhm;
  const f16* Vt = dir ? Vtp : Vth;
  float* O = Out + (size_t)dir * BB * LL * DD;

  const int p = pt * 128 + wv * 32 + l32;  // this lane's p-column

  const f16* Fq_b = Fq + (size_t)b * LL * DD;
  const f16* Fk_b = Fk + (size_t)b * LL * DD;
  const f16* Vt_b = Vt + (size_t)b * DD * LL;

  // Q fragments (B-operand): n=p, k = s*16 + half*8 + j
  f16x8 qf[16];
  {
    const f16* qrow = Fq_b + (size_t)p * DD + half * 8;
#pragma unroll
    for (int s = 0; s < 16; ++s) qf[s] = *(const f16x8*)&qrow[s * 16];
  }

  float m_run = -1e30f, l_part = 0.f;
  f32x16 o[8];
#pragma unroll
  for (int t = 0; t < 8; ++t) o[t] = (f32x16)(0.f);

  // prologue: stage tile 0 into buffer 0
#pragma unroll
  for (int j = 0; j < 4; ++j) {
    int s = wv * 4 + j;
    async_copy16(Fk_b + (size_t)l32 * DD + s * 16 + half * 8, &Kf[0][s][0]);
  }
#pragma unroll
  for (int j = 0; j < 4; ++j) {
    int v = wv * 4 + j;
    int t = v >> 1, h = v & 1;
    async_copy16(Vt_b + (size_t)(t * 32 + l32) * LL + h * 16 + half * 8,
                 &Vf[0][v][0]);
  }

  for (int it = 0; it < 32; ++it) {
    const int cur = it & 1;
    __syncthreads();  // buf[cur] DMA landed; prior reads of buf[cur^1] done

    // stage tile it+1 into buf[cur^1] (overlaps this iter's compute)
    if (it + 1 < 32) {
      const int q1 = (it + 1) * 32;
#pragma unroll
      for (int j = 0; j < 4; ++j) {
        int s = wv * 4 + j;
        async_copy16(Fk_b + (size_t)(q1 + l32) * DD + s * 16 + half * 8,
                     &Kf[cur ^ 1][s][0]);
      }
#pragma unroll
      for (int j = 0; j < 4; ++j) {
        int v = wv * 4 + j;
        int t = v >> 1, h = v & 1;
        async_copy16(Vt_b + (size_t)(t * 32 + l32) * LL + q1 + h * 16 + half * 8,
                     &Vf[cur ^ 1][v][0]);
      }
    }

    // S^T = K Q^T on buf[cur]
    f32x16 S = (f32x16)(0.f);
#pragma unroll
    for (int s = 0; s < 16; ++s) {
      f16x8 kf = *(const f16x8*)&Kf[cur][s][lane * 8];  // conflict-free b128
      S = __builtin_amdgcn_mfma_f32_32x32x16_f16(kf, qf[s], S, 0, 0, 0);
    }

    // in-lane softmax (16 q in-lane + cross-half merge of max)
    float mt = S[0];
#pragma unroll
    for (int r = 1; r < 16; ++r) mt = fmaxf(mt, S[r]);
    mt = fmaxf(mt, __shfl_xor(mt, 32, 64));
    const float mn = fmaxf(m_run, mt);
    float ts = 0.f;
#pragma unroll
    for (int r = 0; r < 16; ++r) {
      S[r] = __expf(S[r] - mn);
      ts += S[r];
    }
    const float alpha = __expf(m_run - mn);
    l_part = l_part * alpha + ts;  // per-lane partial; halves merged at end
    m_run = mn;

    // build P^T B-frags: pack f16 pairs, cross-half exchange (4 shfl)
    u32 pw[8];
#pragma unroll
    for (int i = 0; i < 8; ++i) pw[i] = pack_pkrtz(S[2 * i], S[2 * i + 1]);
    u32 rc[4];
    rc[0] = (u32)__shfl_xor((int)(half ? pw[0] : pw[2]), 32, 64);
    rc[1] = (u32)__shfl_xor((int)(half ? pw[1] : pw[3]), 32, 64);
    rc[2] = (u32)__shfl_xor((int)(half ? pw[4] : pw[6]), 32, 64);
    rc[3] = (u32)__shfl_xor((int)(half ? pw[5] : pw[7]), 32, 64);
    f16x8 pf[2];
#pragma unroll
    for (int h = 0; h < 2; ++h) {
      u32 tmp[4];
      tmp[0] = half ? rc[2 * h] : pw[4 * h];
      tmp[1] = half ? rc[2 * h + 1] : pw[4 * h + 1];
      tmp[2] = half ? pw[4 * h + 2] : rc[2 * h];
      tmp[3] = half ? pw[4 * h + 3] : rc[2 * h + 1];
      __builtin_memcpy(&pf[h], tmp, 16);
    }

    // rescale O^T, then O^T += V^T P^T on buf[cur]
#pragma unroll
    for (int t = 0; t < 8; ++t) o[t] *= alpha;
#pragma unroll
    for (int t = 0; t < 8; ++t) {
      f16x8 v0 = *(const f16x8*)&Vf[cur][t * 2 + 0][lane * 8];
      o[t] = __builtin_amdgcn_mfma_f32_32x32x16_f16(v0, pf[0], o[t], 0, 0, 0);
      f16x8 v1 = *(const f16x8*)&Vf[cur][t * 2 + 1][lane * 8];
      o[t] = __builtin_amdgcn_mfma_f32_32x32x16_f16(v1, pf[1], o[t], 0, 0, 0);
    }
  }

  const float l_run = l_part + __shfl_xor(l_part, 32, 64);
  const float inv = 1.f / l_run;
  // C layout: row(d within t*32) = (r&3) + 8*(r>>2) + 4*half; col = p
  float* orow = O + ((size_t)b * LL + p) * DD;
#pragma unroll
  for (int t = 0; t < 8; ++t) {
#pragma unroll
    for (int g = 0; g < 4; ++g) {
      f32x4 v;
      v[0] = o[t][4 * g + 0] * inv;
      v[1] = o[t][4 * g + 1] * inv;
      v[2] = o[t][4 * g + 2] * inv;
      v[3] = o[t][4 * g + 3] * inv;
      __builtin_nontemporal_store(v, (f32x4*)&orow[t * 32 + 8 * g + 4 * half]);
    }
  }
}

// ---------------------------------------------------------------------------
extern "C" void kernel_launch(void* const* d_in, const int* in_sizes, int n_in,
                              void* d_out, int out_size, void* d_ws,
                              size_t ws_size, hipStream_t stream) {
  const float* premises = (const float*)d_in[0];    // [32,1024,256] fp32
  const float* hypotheses = (const float*)d_in[1];  // [32,1024,256] fp32
  const float* W = (const float*)d_in[2];           // [256,256] fp32
  float* out = (float*)d_out;

  const size_t MF = (size_t)BB * LL * DD;
  f16* Fp = (f16*)d_ws;  // 16 MiB each; ws = 64 MiB exactly
  f16* Fh = Fp + MF;
  f16* Vth = Fh + MF;  // hypotheses^T [B][D][L] f16
  f16* Vtp = Vth + MF; // premises^T   [B][D][L] f16
  // Wt (131 KB) stashed in d_out tail: used only by proj, overwritten by flash
  f16* Wt = (f16*)((char*)d_out + (size_t)out_size * 4 - 256 * 256 * 2);

  // W^T -> f16
  transpose_to_f16<<<dim3(4, 4), 256, 0, stream>>>(W, Wt, 256, 256);
  // F = tanh(X @ W) f16, + fused X^T f16 emit
  proj_mfma<<<dim3(512, 2), 256, 0, stream>>>(premises, hypotheses, Wt, Fp, Fh,
                                              Vtp, Vth);
  // betas + alphas in one swizzled 1D launch: 512 blocks = 2 blocks/CU
  flash_mfma<<<512, 256, 0, stream>>>(Fp, Fh, Vth, Vtp, out);
}